// Round 2
// baseline (250.116 us; speedup 1.0000x reference)
//
#include <hip/hip_runtime.h>
#include <stdint.h>

typedef __attribute__((ext_vector_type(4))) float f32x4;
typedef __attribute__((ext_vector_type(8))) short s16x8;

static constexpr int S_TOK = 4096;   // B*T
static constexpr int CDIM  = 1024;
static constexpr int HDIM  = 1024;
static constexpr int H2    = 2048;
static constexpr int NEXP  = 8;

#define BM 128
#define BN 128
#define BK 32
#define NTHR 512
#define MAXRT 72   // max routed tiles: 8192/128 + 8 partials

__device__ __forceinline__ unsigned short f2bf(float f) {
  union { float f; uint32_t u; } c; c.f = f;
  uint32_t u = c.u;
  u += 0x7fffu + ((u >> 16) & 1u);   // RNE
  return (unsigned short)(u >> 16);
}

__device__ __forceinline__ float bf2f(unsigned short u) {
  return __uint_as_float(((uint32_t)u) << 16);
}

__device__ __forceinline__ void gload16(const void* g, void* l) {
  __builtin_amdgcn_global_load_lds(
      (const __attribute__((address_space(1))) void*)g,
      (__attribute__((address_space(3))) void*)l, 16, 0, 0);
}

// ---------- cast fp32 -> bf16 (x4) ----------
__global__ void cast_bf16_kernel(const float* __restrict__ src,
                                 unsigned short* __restrict__ dst, int n4) {
  int i = blockIdx.x * blockDim.x + threadIdx.x;
  const int st = gridDim.x * blockDim.x;
  for (; i < n4; i += st) {
    float4 v = reinterpret_cast<const float4*>(src)[i];
    ushort4 o;
    o.x = f2bf(v.x); o.y = f2bf(v.y); o.z = f2bf(v.z); o.w = f2bf(v.w);
    reinterpret_cast<ushort4*>(dst)[i] = o;
  }
}

// ---------- w_in prep: src fp32 [C, 2H] -> dst bf16 [4096, C] with part-interleave ----------
// dst row (within half) = (h&15) + ((h>>4)<<5) + (part<<4); half offset 2048 for w1s.
__global__ void wprep_in_kernel(const float* __restrict__ wsi, const float* __restrict__ w1s,
                                unsigned short* __restrict__ dst) {
  __shared__ float t[32][33];
  const float* src = blockIdx.z ? w1s : wsi;
  const int halfoff = blockIdx.z ? 2048 : 0;
  const int r0 = blockIdx.y * 32;   // C dim
  const int c0 = blockIdx.x * 32;   // 2H dim
  const int tid = threadIdx.x;
#pragma unroll
  for (int i = 0; i < 4; ++i) {
    int idx = tid + i * 256;
    int r = idx >> 5, c = idx & 31;
    t[r][c] = src[(size_t)(r0 + r) * H2 + c0 + c];
  }
  __syncthreads();
#pragma unroll
  for (int i = 0; i < 4; ++i) {
    int idx = tid + i * 256;
    int r = idx >> 5, c = idx & 31;
    const int ccol = c0 + r;
    const int part = ccol >> 10, h = ccol & 1023;
    const int drow = halfoff + (h & 15) + ((h >> 4) << 5) + (part << 4);
    dst[(size_t)drow * CDIM + r0 + c] = f2bf(t[c][r]);
  }
}

// ---------- plain transpose + cast: src fp32 [R, Cc] -> dst bf16 [Cc, R] ----------
__global__ void transpose_cast_kernel(const float* __restrict__ src,
                                      unsigned short* __restrict__ dst,
                                      int R, int Cc) {
  __shared__ float t[32][33];
  const size_t zoff = (size_t)blockIdx.z * R * Cc;
  src += zoff; dst += zoff;
  const int r0 = blockIdx.y * 32;
  const int c0 = blockIdx.x * 32;
  const int tid = threadIdx.x;
#pragma unroll
  for (int i = 0; i < 4; ++i) {
    int idx = tid + i * 256;
    int r = idx >> 5, c = idx & 31;
    t[r][c] = src[(size_t)(r0 + r) * Cc + c0 + c];
  }
  __syncthreads();
#pragma unroll
  for (int i = 0; i < 4; ++i) {
    int idx = tid + i * 256;
    int r = idx >> 5, c = idx & 31;
    dst[(size_t)(c0 + r) * R + r0 + c] = f2bf(t[c][r]);
  }
}

// ---------- router: fp32, top-2, atomic slot assignment ----------
__global__ void router_kernel(const float* __restrict__ x, const float* __restrict__ wg,
                              const float* __restrict__ gb,
                              int2* __restrict__ ti_e, int2* __restrict__ ti_slot,
                              float2* __restrict__ ti_w, int* __restrict__ cnt) {
  const int l = threadIdx.x & 63;
  const int wid = threadIdx.x >> 6;
  const int s = blockIdx.x * 4 + wid;
  const float* xr = x + (size_t)s * CDIM;
  float acc[NEXP];
#pragma unroll
  for (int e = 0; e < NEXP; ++e) acc[e] = 0.f;
  for (int c = l; c < CDIM; c += 64) {
    float xv = xr[c];
    const float* wr_ = wg + (size_t)c * NEXP;
#pragma unroll
    for (int e = 0; e < NEXP; ++e) acc[e] += xv * wr_[e];
  }
#pragma unroll
  for (int e = 0; e < NEXP; ++e) {
#pragma unroll
    for (int off = 32; off > 0; off >>= 1) acc[e] += __shfl_xor(acc[e], off);
    acc[e] += gb[e];
  }
  float m = acc[0];
#pragma unroll
  for (int e = 1; e < NEXP; ++e) m = fmaxf(m, acc[e]);
  float ex[NEXP], sum = 0.f;
#pragma unroll
  for (int e = 0; e < NEXP; ++e) { ex[e] = __expf(acc[e] - m); sum += ex[e]; }
  int i0 = 0;
#pragma unroll
  for (int e = 1; e < NEXP; ++e) if (acc[e] > acc[i0]) i0 = e;  // lowest idx on tie
  int i1 = (i0 == 0) ? 1 : 0;
#pragma unroll
  for (int e = 0; e < NEXP; ++e) {
    if (e == i0) continue;
    if (acc[e] > acc[i1]) i1 = e;
  }
  if (l == 0) {
    const float inv = 1.f / sum;
    ti_e[s] = make_int2(i0, i1);
    int s0 = atomicAdd(&cnt[i0], 1);
    int s1 = atomicAdd(&cnt[i1], 1);
    ti_slot[s] = make_int2(s0, s1);
    ti_w[s] = make_float2(ex[i0] * inv, ex[i1] * inv);
  }
}

// ---------- build: offsets + gather index list ----------
__global__ void build_kernel(const int* __restrict__ cnt, int* __restrict__ offs,
                             const int2* __restrict__ ti_e, const int2* __restrict__ ti_slot,
                             int* __restrict__ gidx) {
  __shared__ int so[NEXP];
  if (threadIdx.x == 0) {
    int a = 0;
#pragma unroll
    for (int e = 0; e < NEXP; ++e) { offs[e] = a; so[e] = a; a += cnt[e]; }
    offs[NEXP] = a;
  }
  __syncthreads();
  for (int s = threadIdx.x; s < S_TOK; s += blockDim.x) {
    int2 e = ti_e[s]; int2 sl = ti_slot[s];
    gidx[so[e.x] + sl.x] = s;
    gidx[so[e.y] + sl.y] = s;
  }
}

// ---------- shared MFMA core (m97 structure) ----------
__device__ __forceinline__ void ktile_mfma(const unsigned short* As, const unsigned short* Bs,
                                           int lr, int lk, int wr, int wc, f32x4 acc[2][4]) {
  s16x8 a[2], b[4];
#pragma unroll
  for (int fm = 0; fm < 2; ++fm)
    a[fm] = *reinterpret_cast<const s16x8*>(As + (wr * 32 + fm * 16 + lr) * BK + lk);
#pragma unroll
  for (int fn = 0; fn < 4; ++fn)
    b[fn] = *reinterpret_cast<const s16x8*>(Bs + (wc * 64 + fn * 16 + lr) * BK + lk);
#pragma unroll
  for (int fm = 0; fm < 2; ++fm)
#pragma unroll
    for (int fn = 0; fn < 4; ++fn)
      acc[fm][fn] = __builtin_amdgcn_mfma_f32_16x16x32_bf16(a[fm], b[fn], acc[fm][fn], 0, 0, 0);
}

__device__ __forceinline__ void gemm_core(const unsigned short* __restrict__ ga,
                                          const unsigned short* __restrict__ gb,
                                          unsigned short* As, unsigned short* Bs,
                                          int tid, int lr, int lk, int wr, int wc,
                                          f32x4 acc[2][4]) {
  for (int k0 = 0; k0 < 1024; k0 += BK) {
    gload16(ga + k0, As + tid * 8);
    gload16(gb + k0, Bs + tid * 8);
    __syncthreads();
    ktile_mfma(As, Bs, lr, lk, wr, wc, acc);
    __syncthreads();
  }
}

// ---------- GEMM1: hid = swiglu(x @ [wsi|w1s]) fused epilogue -> Hs, Hr bf16 ----------
__global__ __launch_bounds__(NTHR) void gemm1_kernel(
    const unsigned short* __restrict__ xb, const unsigned short* __restrict__ w12i,
    unsigned short* __restrict__ Hs, unsigned short* __restrict__ Hr) {
  __shared__ unsigned short As[BM * BK];
  __shared__ unsigned short Bs[BN * BK];
  const int tid = threadIdx.x;
  const int l = tid & 63, wid = tid >> 6;
  const int wr = wid >> 1, wc = wid & 1;
  const int lr = l & 15, lk = (l >> 4) << 3;
  const int m0 = blockIdx.x * BM, n0 = blockIdx.y * BN;
  f32x4 acc[2][4] = {};
  const unsigned short* ga = xb + (size_t)(m0 + (tid >> 2)) * CDIM + ((tid & 3) << 3);
  const unsigned short* gb = w12i + (size_t)(n0 + (tid >> 2)) * CDIM + ((tid & 3) << 3);
  gemm_core(ga, gb, As, Bs, tid, lr, lk, wr, wc, acc);

  unsigned short* Hbuf = (n0 < 2048) ? Hs : Hr;
  const int rb = m0 + wr * 32 + ((l >> 4) << 2);
  const int hbase = ((n0 & 2047) >> 1) + wc * 32;
#pragma unroll
  for (int fm = 0; fm < 2; ++fm)
#pragma unroll
    for (int j = 0; j < 2; ++j)
#pragma unroll
      for (int r = 0; r < 4; ++r) {
        float a = acc[fm][2 * j][r];
        float b = acc[fm][2 * j + 1][r];
        float hv = (a / (1.f + __expf(-a))) * b;
        Hbuf[(size_t)(rb + fm * 16 + r) * HDIM + hbase + j * 16 + lr] = f2bf(hv);
      }
}

// ---------- GEMM2 merged: dense shared-out (fp32 -> d_out) + ragged routed (bf16 -> Eout) ----------
__global__ __launch_bounds__(NTHR) void gemm2_kernel(
    const unsigned short* __restrict__ Hs, const unsigned short* __restrict__ Hr,
    const unsigned short* __restrict__ wso_t, const unsigned short* __restrict__ w2t,
    const int* __restrict__ cnt, const int* __restrict__ offs, const int* __restrict__ gidx,
    float* __restrict__ out, unsigned short* __restrict__ Eout) {
  __shared__ unsigned short As[BM * BK];
  __shared__ unsigned short Bs[BN * BK];
  const int tid = threadIdx.x;
  const int l = tid & 63, wid = tid >> 6;
  const int wr = wid >> 1, wc = wid & 1;
  const int lr = l & 15, lk = (l >> 4) << 3;
  const int n0 = blockIdx.y * BN;
  const int bx = blockIdx.x;
  f32x4 acc[2][4] = {};
  const int cb = n0 + wc * 64 + lr;

  if (bx < 32) {
    // dense shared-expert out tile
    const int m0 = bx * BM;
    const unsigned short* ga = Hs + (size_t)(m0 + (tid >> 2)) * HDIM + ((tid & 3) << 3);
    const unsigned short* gb = wso_t + (size_t)(n0 + (tid >> 2)) * HDIM + ((tid & 3) << 3);
    gemm_core(ga, gb, As, Bs, tid, lr, lk, wr, wc, acc);
    const int rb = m0 + wr * 32 + ((l >> 4) << 2);
#pragma unroll
    for (int fm = 0; fm < 2; ++fm)
#pragma unroll
      for (int fn = 0; fn < 4; ++fn)
#pragma unroll
        for (int r = 0; r < 4; ++r)
          out[(size_t)(rb + fm * 16 + r) * CDIM + cb + fn * 16] = acc[fm][fn][r];
  } else {
    // ragged routed tile: find (expert e, m-tile mt)
    int t = bx - 32;
    int e = 0, cnte = 0;
    bool found = false;
#pragma unroll
    for (int ee = 0; ee < NEXP; ++ee) {
      int c = cnt[ee];
      int nt = (c + BM - 1) >> 7;
      if (!found) {
        if (t < nt) { e = ee; cnte = c; found = true; }
        else t -= nt;
      }
    }
    if (!found) return;
    const int mt = t;
    const int base = offs[e];
    const int grow = mt * BM + (tid >> 2);
    const int tok = gidx[base + min(grow, cnte - 1)];
    const unsigned short* ga = Hr + (size_t)tok * HDIM + ((tid & 3) << 3);
    const unsigned short* gb = w2t + (size_t)e * CDIM * HDIM +
                               (size_t)(n0 + (tid >> 2)) * HDIM + ((tid & 3) << 3);
    gemm_core(ga, gb, As, Bs, tid, lr, lk, wr, wc, acc);
    const int lrow = wr * 32 + ((l >> 4) << 2);
#pragma unroll
    for (int fm = 0; fm < 2; ++fm)
#pragma unroll
      for (int fn = 0; fn < 4; ++fn)
#pragma unroll
        for (int r = 0; r < 4; ++r) {
          const int rloc = mt * BM + lrow + fm * 16 + r;
          if (rloc < cnte)
            Eout[(size_t)(base + rloc) * CDIM + cb + fn * 16] = f2bf(acc[fm][fn][r]);
        }
  }
}

// ---------- scatter: out[s] += w0*Eout[p0] + w1*Eout[p1] ----------
__global__ void scatter_kernel(float* __restrict__ out, const unsigned short* __restrict__ Eout,
                               const int2* __restrict__ ti_e, const int2* __restrict__ ti_slot,
                               const float2* __restrict__ ti_w, const int* __restrict__ offs) {
  const int total = S_TOK * (CDIM / 8);
  int i = blockIdx.x * blockDim.x + threadIdx.x;
  const int st = gridDim.x * blockDim.x;
  for (; i < total; i += st) {
    const int s = i >> 7;
    const int j = (i & 127) << 3;
    const int2 e = ti_e[s];
    const int2 sl = ti_slot[s];
    const float2 wv = ti_w[s];
    const int p0 = offs[e.x] + sl.x;
    const int p1 = offs[e.y] + sl.y;
    const ushort4* e0 = reinterpret_cast<const ushort4*>(Eout + (size_t)p0 * CDIM + j);
    const ushort4* e1 = reinterpret_cast<const ushort4*>(Eout + (size_t)p1 * CDIM + j);
    float* op = out + (size_t)s * CDIM + j;
#pragma unroll
    for (int q = 0; q < 2; ++q) {
      ushort4 a = e0[q], b = e1[q];
      float4 o = reinterpret_cast<float4*>(op)[q];
      o.x += wv.x * bf2f(a.x) + wv.y * bf2f(b.x);
      o.y += wv.x * bf2f(a.y) + wv.y * bf2f(b.y);
      o.z += wv.x * bf2f(a.z) + wv.y * bf2f(b.z);
      o.w += wv.x * bf2f(a.w) + wv.y * bf2f(b.w);
      reinterpret_cast<float4*>(op)[q] = o;
    }
  }
}

extern "C" void kernel_launch(void* const* d_in, const int* in_sizes, int n_in,
                              void* d_out, int out_size, void* d_ws, size_t ws_size,
                              hipStream_t stream) {
  (void)in_sizes; (void)n_in; (void)out_size; (void)ws_size;
  const float* x   = (const float*)d_in[0];
  const float* wsi = (const float*)d_in[1];   // [C, 2H]
  const float* wso = (const float*)d_in[2];   // [H, C]
  const float* w1s = (const float*)d_in[3];   // [C, 2H]
  const float* w2  = (const float*)d_in[4];   // [E, H, C]
  const float* wg  = (const float*)d_in[5];   // [C, E]
  const float* gb  = (const float*)d_in[6];   // [E]
  float* out = (float*)d_out;

  char* w = (char*)d_ws;
  auto alloc = [&](size_t bytes) {
    char* p = w; w += (bytes + 255) & ~(size_t)255; return p;
  };
  unsigned short* xb    = (unsigned short*)alloc((size_t)S_TOK * CDIM * 2);
  unsigned short* w12i  = (unsigned short*)alloc((size_t)2 * H2 * CDIM * 2);
  unsigned short* wso_t = (unsigned short*)alloc((size_t)CDIM * HDIM * 2);
  unsigned short* w2t   = (unsigned short*)alloc((size_t)NEXP * CDIM * HDIM * 2);
  unsigned short* Hs    = (unsigned short*)alloc((size_t)S_TOK * HDIM * 2);
  unsigned short* Hr    = (unsigned short*)alloc((size_t)S_TOK * HDIM * 2);
  unsigned short* Eout  = (unsigned short*)alloc((size_t)2 * S_TOK * CDIM * 2);
  int2*   ti_e   = (int2*)alloc((size_t)S_TOK * 8);
  int2*   ti_slot= (int2*)alloc((size_t)S_TOK * 8);
  float2* ti_w   = (float2*)alloc((size_t)S_TOK * 8);
  int*    cnt    = (int*)alloc(64);
  int*    offs   = (int*)alloc(64);
  int*    gidx   = (int*)alloc((size_t)2 * S_TOK * 4);

  hipMemsetAsync(cnt, 0, NEXP * sizeof(int), stream);

  // prep
  cast_bf16_kernel<<<2048, 256, 0, stream>>>(x, xb, S_TOK * CDIM / 4);
  wprep_in_kernel<<<dim3(H2 / 32, CDIM / 32, 2), 256, 0, stream>>>(wsi, w1s, w12i);
  transpose_cast_kernel<<<dim3(CDIM / 32, HDIM / 32, 1), 256, 0, stream>>>(wso, wso_t, HDIM, CDIM);
  transpose_cast_kernel<<<dim3(CDIM / 32, HDIM / 32, NEXP), 256, 0, stream>>>(w2, w2t, HDIM, CDIM);

  // router + gather build
  router_kernel<<<S_TOK / 4, 256, 0, stream>>>(x, wg, gb, ti_e, ti_slot, ti_w, cnt);
  build_kernel<<<1, 256, 0, stream>>>(cnt, offs, ti_e, ti_slot, gidx);

  // stage 1: both hiddens in one GEMM, swiglu fused
  gemm1_kernel<<<dim3(S_TOK / BM, (2 * H2) / BN), NTHR, 0, stream>>>(xb, w12i, Hs, Hr);

  // stage 2: dense shared-out + ragged routed experts
  gemm2_kernel<<<dim3(32 + MAXRT, CDIM / BN), NTHR, 0, stream>>>(
      Hs, Hr, wso_t, w2t, cnt, offs, gidx, out, Eout);

  // scatter routed contributions into out
  scatter_kernel<<<2048, 256, 0, stream>>>(out, Eout, ti_e, ti_slot, ti_w, offs);
}

// Round 3
// 154.750 us; speedup vs baseline: 1.6163x; 1.6163x over previous
//
#include <hip/hip_runtime.h>
#include <stdint.h>

typedef __attribute__((ext_vector_type(4))) float f32x4;
typedef __attribute__((ext_vector_type(8))) short s16x8;

static constexpr int S_TOK = 4096;   // B*T
static constexpr int CDIM  = 1024;
static constexpr int HDIM  = 1024;
static constexpr int H2    = 2048;
static constexpr int NEXP  = 8;

#define BM 128
#define BN 128
#define BK 32
#define NTHR 512
#define MAXRT 72   // max routed tiles: 8192/128 + 8 partials

__device__ __forceinline__ unsigned short f2bf(float f) {
  union { float f; uint32_t u; } c; c.f = f;
  uint32_t u = c.u;
  u += 0x7fffu + ((u >> 16) & 1u);   // RNE
  return (unsigned short)(u >> 16);
}

__device__ __forceinline__ float bf2f(unsigned short u) {
  return __uint_as_float(((uint32_t)u) << 16);
}

__device__ __forceinline__ void gload16(const void* g, void* l) {
  __builtin_amdgcn_global_load_lds(
      (const __attribute__((address_space(1))) void*)g,
      (__attribute__((address_space(3))) void*)l, 16, 0, 0);
}

// ---------- cast fp32 -> bf16 (x4) ----------
__global__ void cast_bf16_kernel(const float* __restrict__ src,
                                 unsigned short* __restrict__ dst, int n4) {
  int i = blockIdx.x * blockDim.x + threadIdx.x;
  const int st = gridDim.x * blockDim.x;
  for (; i < n4; i += st) {
    float4 v = reinterpret_cast<const float4*>(src)[i];
    ushort4 o;
    o.x = f2bf(v.x); o.y = f2bf(v.y); o.z = f2bf(v.z); o.w = f2bf(v.w);
    reinterpret_cast<ushort4*>(dst)[i] = o;
  }
}

// ---------- w_in prep: src fp32 [C, 2H] -> dst bf16 [4096, C] with part-interleave ----------
// dst row (within half) = (h&15) + ((h>>4)<<5) + (part<<4); half offset 2048 for w1s.
__global__ void wprep_in_kernel(const float* __restrict__ wsi, const float* __restrict__ w1s,
                                unsigned short* __restrict__ dst) {
  __shared__ float t[32][33];
  const float* src = blockIdx.z ? w1s : wsi;
  const int halfoff = blockIdx.z ? 2048 : 0;
  const int r0 = blockIdx.y * 32;   // C dim
  const int c0 = blockIdx.x * 32;   // 2H dim
  const int tid = threadIdx.x;
#pragma unroll
  for (int i = 0; i < 4; ++i) {
    int idx = tid + i * 256;
    int r = idx >> 5, c = idx & 31;
    t[r][c] = src[(size_t)(r0 + r) * H2 + c0 + c];
  }
  __syncthreads();
#pragma unroll
  for (int i = 0; i < 4; ++i) {
    int idx = tid + i * 256;
    int r = idx >> 5, c = idx & 31;
    const int ccol = c0 + r;
    const int part = ccol >> 10, h = ccol & 1023;
    const int drow = halfoff + (h & 15) + ((h >> 4) << 5) + (part << 4);
    dst[(size_t)drow * CDIM + r0 + c] = f2bf(t[c][r]);
  }
}

// ---------- plain transpose + cast: src fp32 [R, Cc] -> dst bf16 [Cc, R] ----------
__global__ void transpose_cast_kernel(const float* __restrict__ src,
                                      unsigned short* __restrict__ dst,
                                      int R, int Cc) {
  __shared__ float t[32][33];
  const size_t zoff = (size_t)blockIdx.z * R * Cc;
  src += zoff; dst += zoff;
  const int r0 = blockIdx.y * 32;
  const int c0 = blockIdx.x * 32;
  const int tid = threadIdx.x;
#pragma unroll
  for (int i = 0; i < 4; ++i) {
    int idx = tid + i * 256;
    int r = idx >> 5, c = idx & 31;
    t[r][c] = src[(size_t)(r0 + r) * Cc + c0 + c];
  }
  __syncthreads();
#pragma unroll
  for (int i = 0; i < 4; ++i) {
    int idx = tid + i * 256;
    int r = idx >> 5, c = idx & 31;
    dst[(size_t)(c0 + r) * R + r0 + c] = f2bf(t[c][r]);
  }
}

// ---------- router: fp32 logits, softmax, top-2. NO atomics. ----------
__global__ void router_kernel(const float* __restrict__ x, const float* __restrict__ wg,
                              const float* __restrict__ gb,
                              int2* __restrict__ ti_e, float2* __restrict__ ti_w) {
  const int l = threadIdx.x & 63;
  const int wid = threadIdx.x >> 6;
  const int s = blockIdx.x * 4 + wid;
  const float* xr = x + (size_t)s * CDIM;
  float acc[NEXP];
#pragma unroll
  for (int e = 0; e < NEXP; ++e) acc[e] = 0.f;
  for (int c = l; c < CDIM; c += 64) {
    float xv = xr[c];
    const float* wr_ = wg + (size_t)c * NEXP;
#pragma unroll
    for (int e = 0; e < NEXP; ++e) acc[e] += xv * wr_[e];
  }
#pragma unroll
  for (int e = 0; e < NEXP; ++e) {
#pragma unroll
    for (int off = 32; off > 0; off >>= 1) acc[e] += __shfl_xor(acc[e], off);
    acc[e] += gb[e];
  }
  float m = acc[0];
#pragma unroll
  for (int e = 1; e < NEXP; ++e) m = fmaxf(m, acc[e]);
  float ex[NEXP], sum = 0.f;
#pragma unroll
  for (int e = 0; e < NEXP; ++e) { ex[e] = __expf(acc[e] - m); sum += ex[e]; }
  int i0 = 0;
#pragma unroll
  for (int e = 1; e < NEXP; ++e) if (acc[e] > acc[i0]) i0 = e;  // lowest idx on tie
  int i1 = (i0 == 0) ? 1 : 0;
#pragma unroll
  for (int e = 0; e < NEXP; ++e) {
    if (e == i0) continue;
    if (acc[e] > acc[i1]) i1 = e;
  }
  if (l == 0) {
    const float inv = 1.f / sum;
    ti_e[s] = make_int2(i0, i1);
    ti_w[s] = make_float2(ex[i0] * inv, ex[i1] * inv);
  }
}

// ---------- build: deterministic counts/offsets/ranks/gather via ballot scan ----------
// 1024 threads, 64 groups of 64 tokens. Order within expert: (token, pick) lexicographic.
__global__ __launch_bounds__(1024) void build_kernel(
    const int2* __restrict__ ti_e,
    int* __restrict__ cnt, int* __restrict__ offs,
    int* __restrict__ gidx, int2* __restrict__ ti_slot) {
  __shared__ int gcnt[64][NEXP];
  __shared__ int gbase[64][NEXP];
  __shared__ int eoff[NEXP];
  const int tid = threadIdx.x;
  const int wid = tid >> 6, lane = tid & 63;

  // phase 1: per-group per-expert counts
  for (int p = 0; p < 4; ++p) {
    const int g = p * 16 + wid;
    const int2 e = ti_e[g * 64 + lane];
#pragma unroll
    for (int ex = 0; ex < NEXP; ++ex) {
      uint64_t b0 = __ballot(e.x == ex);
      uint64_t b1 = __ballot(e.y == ex);
      if (lane == 0) gcnt[g][ex] = __popcll(b0) + __popcll(b1);
    }
  }
  __syncthreads();
  // phase 2a: prefix across 64 groups for each expert
  if (tid < NEXP) {
    const int ex = tid;
    int a = 0;
    for (int g = 0; g < 64; ++g) { gbase[g][ex] = a; a += gcnt[g][ex]; }
    eoff[ex] = a;   // per-expert total
  }
  __syncthreads();
  // phase 2b: expert exclusive offsets
  if (tid == 0) {
    int a = 0;
#pragma unroll
    for (int ex = 0; ex < NEXP; ++ex) {
      const int c = eoff[ex];
      offs[ex] = a; cnt[ex] = c; eoff[ex] = a; a += c;
    }
    offs[NEXP] = a;
  }
  __syncthreads();
  // phase 3: ranks + gather-list writes
  for (int p = 0; p < 4; ++p) {
    const int g = p * 16 + wid;
    const int s = g * 64 + lane;
    const int2 e = ti_e[s];
    const uint64_t below = (lane == 0) ? 0ull : (~0ull >> (64 - lane));
    const uint64_t beloweq = below | (1ull << lane);
    int slot0 = 0, slot1 = 0;
#pragma unroll
    for (int ex = 0; ex < NEXP; ++ex) {
      uint64_t b0 = __ballot(e.x == ex);
      uint64_t b1 = __ballot(e.y == ex);
      const int base = gbase[g][ex];
      if (e.x == ex) slot0 = base + __popcll(b0 & below) + __popcll(b1 & below);
      if (e.y == ex) slot1 = base + __popcll(b0 & beloweq) + __popcll(b1 & below);
    }
    ti_slot[s] = make_int2(slot0, slot1);
    gidx[eoff[e.x] + slot0] = s;
    gidx[eoff[e.y] + slot1] = s;
  }
}

// ---------- shared MFMA core (m97 structure) ----------
__device__ __forceinline__ void ktile_mfma(const unsigned short* As, const unsigned short* Bs,
                                           int lr, int lk, int wr, int wc, f32x4 acc[2][4]) {
  s16x8 a[2], b[4];
#pragma unroll
  for (int fm = 0; fm < 2; ++fm)
    a[fm] = *reinterpret_cast<const s16x8*>(As + (wr * 32 + fm * 16 + lr) * BK + lk);
#pragma unroll
  for (int fn = 0; fn < 4; ++fn)
    b[fn] = *reinterpret_cast<const s16x8*>(Bs + (wc * 64 + fn * 16 + lr) * BK + lk);
#pragma unroll
  for (int fm = 0; fm < 2; ++fm)
#pragma unroll
    for (int fn = 0; fn < 4; ++fn)
      acc[fm][fn] = __builtin_amdgcn_mfma_f32_16x16x32_bf16(a[fm], b[fn], acc[fm][fn], 0, 0, 0);
}

__device__ __forceinline__ void gemm_core(const unsigned short* __restrict__ ga,
                                          const unsigned short* __restrict__ gb,
                                          unsigned short* As, unsigned short* Bs,
                                          int tid, int lr, int lk, int wr, int wc,
                                          f32x4 acc[2][4]) {
  for (int k0 = 0; k0 < 1024; k0 += BK) {
    gload16(ga + k0, As + tid * 8);
    gload16(gb + k0, Bs + tid * 8);
    __syncthreads();
    ktile_mfma(As, Bs, lr, lk, wr, wc, acc);
    __syncthreads();
  }
}

// ---------- GEMM1: hid = swiglu(x @ [wsi|w1s]) fused epilogue -> Hs, Hr bf16 ----------
__global__ __launch_bounds__(NTHR) void gemm1_kernel(
    const unsigned short* __restrict__ xb, const unsigned short* __restrict__ w12i,
    unsigned short* __restrict__ Hs, unsigned short* __restrict__ Hr) {
  __shared__ unsigned short As[BM * BK];
  __shared__ unsigned short Bs[BN * BK];
  const int tid = threadIdx.x;
  const int l = tid & 63, wid = tid >> 6;
  const int wr = wid >> 1, wc = wid & 1;
  const int lr = l & 15, lk = (l >> 4) << 3;
  const int m0 = blockIdx.x * BM, n0 = blockIdx.y * BN;
  f32x4 acc[2][4] = {};
  const unsigned short* ga = xb + (size_t)(m0 + (tid >> 2)) * CDIM + ((tid & 3) << 3);
  const unsigned short* gb = w12i + (size_t)(n0 + (tid >> 2)) * CDIM + ((tid & 3) << 3);
  gemm_core(ga, gb, As, Bs, tid, lr, lk, wr, wc, acc);

  unsigned short* Hbuf = (n0 < 2048) ? Hs : Hr;
  const int rb = m0 + wr * 32 + ((l >> 4) << 2);
  const int hbase = ((n0 & 2047) >> 1) + wc * 32;
#pragma unroll
  for (int fm = 0; fm < 2; ++fm)
#pragma unroll
    for (int j = 0; j < 2; ++j)
#pragma unroll
      for (int r = 0; r < 4; ++r) {
        float a = acc[fm][2 * j][r];
        float b = acc[fm][2 * j + 1][r];
        float hv = (a / (1.f + __expf(-a))) * b;
        Hbuf[(size_t)(rb + fm * 16 + r) * HDIM + hbase + j * 16 + lr] = f2bf(hv);
      }
}

// ---------- GEMM2 merged: dense shared-out (fp32 -> d_out) + ragged routed (bf16 -> Eout) ----------
__global__ __launch_bounds__(NTHR) void gemm2_kernel(
    const unsigned short* __restrict__ Hs, const unsigned short* __restrict__ Hr,
    const unsigned short* __restrict__ wso_t, const unsigned short* __restrict__ w2t,
    const int* __restrict__ cnt, const int* __restrict__ offs, const int* __restrict__ gidx,
    float* __restrict__ out, unsigned short* __restrict__ Eout) {
  __shared__ unsigned short As[BM * BK];
  __shared__ unsigned short Bs[BN * BK];
  const int tid = threadIdx.x;
  const int l = tid & 63, wid = tid >> 6;
  const int wr = wid >> 1, wc = wid & 1;
  const int lr = l & 15, lk = (l >> 4) << 3;
  const int n0 = blockIdx.y * BN;
  const int bx = blockIdx.x;
  f32x4 acc[2][4] = {};
  const int cb = n0 + wc * 64 + lr;

  if (bx < 32) {
    // dense shared-expert out tile
    const int m0 = bx * BM;
    const unsigned short* ga = Hs + (size_t)(m0 + (tid >> 2)) * HDIM + ((tid & 3) << 3);
    const unsigned short* gb = wso_t + (size_t)(n0 + (tid >> 2)) * HDIM + ((tid & 3) << 3);
    gemm_core(ga, gb, As, Bs, tid, lr, lk, wr, wc, acc);
    const int rb = m0 + wr * 32 + ((l >> 4) << 2);
#pragma unroll
    for (int fm = 0; fm < 2; ++fm)
#pragma unroll
      for (int fn = 0; fn < 4; ++fn)
#pragma unroll
        for (int r = 0; r < 4; ++r)
          out[(size_t)(rb + fm * 16 + r) * CDIM + cb + fn * 16] = acc[fm][fn][r];
  } else {
    // ragged routed tile: find (expert e, m-tile mt)
    int t = bx - 32;
    int e = 0, cnte = 0;
    bool found = false;
#pragma unroll
    for (int ee = 0; ee < NEXP; ++ee) {
      int c = cnt[ee];
      int nt = (c + BM - 1) >> 7;
      if (!found) {
        if (t < nt) { e = ee; cnte = c; found = true; }
        else t -= nt;
      }
    }
    if (!found) return;
    const int mt = t;
    const int base = offs[e];
    const int grow = mt * BM + (tid >> 2);
    const int tok = gidx[base + min(grow, cnte - 1)];
    const unsigned short* ga = Hr + (size_t)tok * HDIM + ((tid & 3) << 3);
    const unsigned short* gb = w2t + (size_t)e * CDIM * HDIM +
                               (size_t)(n0 + (tid >> 2)) * HDIM + ((tid & 3) << 3);
    gemm_core(ga, gb, As, Bs, tid, lr, lk, wr, wc, acc);
    const int lrow = wr * 32 + ((l >> 4) << 2);
#pragma unroll
    for (int fm = 0; fm < 2; ++fm)
#pragma unroll
      for (int fn = 0; fn < 4; ++fn)
#pragma unroll
        for (int r = 0; r < 4; ++r) {
          const int rloc = mt * BM + lrow + fm * 16 + r;
          if (rloc < cnte)
            Eout[(size_t)(base + rloc) * CDIM + cb + fn * 16] = f2bf(acc[fm][fn][r]);
        }
  }
}

// ---------- scatter: out[s] += w0*Eout[p0] + w1*Eout[p1] ----------
__global__ void scatter_kernel(float* __restrict__ out, const unsigned short* __restrict__ Eout,
                               const int2* __restrict__ ti_e, const int2* __restrict__ ti_slot,
                               const float2* __restrict__ ti_w, const int* __restrict__ offs) {
  const int total = S_TOK * (CDIM / 8);
  int i = blockIdx.x * blockDim.x + threadIdx.x;
  const int st = gridDim.x * blockDim.x;
  for (; i < total; i += st) {
    const int s = i >> 7;
    const int j = (i & 127) << 3;
    const int2 e = ti_e[s];
    const int2 sl = ti_slot[s];
    const float2 wv = ti_w[s];
    const int p0 = offs[e.x] + sl.x;
    const int p1 = offs[e.y] + sl.y;
    const ushort4* e0 = reinterpret_cast<const ushort4*>(Eout + (size_t)p0 * CDIM + j);
    const ushort4* e1 = reinterpret_cast<const ushort4*>(Eout + (size_t)p1 * CDIM + j);
    float* op = out + (size_t)s * CDIM + j;
#pragma unroll
    for (int q = 0; q < 2; ++q) {
      ushort4 a = e0[q], b = e1[q];
      float4 o = reinterpret_cast<float4*>(op)[q];
      o.x += wv.x * bf2f(a.x) + wv.y * bf2f(b.x);
      o.y += wv.x * bf2f(a.y) + wv.y * bf2f(b.y);
      o.z += wv.x * bf2f(a.z) + wv.y * bf2f(b.z);
      o.w += wv.x * bf2f(a.w) + wv.y * bf2f(b.w);
      reinterpret_cast<float4*>(op)[q] = o;
    }
  }
}

extern "C" void kernel_launch(void* const* d_in, const int* in_sizes, int n_in,
                              void* d_out, int out_size, void* d_ws, size_t ws_size,
                              hipStream_t stream) {
  (void)in_sizes; (void)n_in; (void)out_size; (void)ws_size;
  const float* x   = (const float*)d_in[0];
  const float* wsi = (const float*)d_in[1];   // [C, 2H]
  const float* wso = (const float*)d_in[2];   // [H, C]
  const float* w1s = (const float*)d_in[3];   // [C, 2H]
  const float* w2  = (const float*)d_in[4];   // [E, H, C]
  const float* wg  = (const float*)d_in[5];   // [C, E]
  const float* gb  = (const float*)d_in[6];   // [E]
  float* out = (float*)d_out;

  char* w = (char*)d_ws;
  auto alloc = [&](size_t bytes) {
    char* p = w; w += (bytes + 255) & ~(size_t)255; return p;
  };
  unsigned short* xb    = (unsigned short*)alloc((size_t)S_TOK * CDIM * 2);
  unsigned short* w12i  = (unsigned short*)alloc((size_t)2 * H2 * CDIM * 2);
  unsigned short* wso_t = (unsigned short*)alloc((size_t)CDIM * HDIM * 2);
  unsigned short* w2t   = (unsigned short*)alloc((size_t)NEXP * CDIM * HDIM * 2);
  unsigned short* Hs    = (unsigned short*)alloc((size_t)S_TOK * HDIM * 2);
  unsigned short* Hr    = (unsigned short*)alloc((size_t)S_TOK * HDIM * 2);
  unsigned short* Eout  = (unsigned short*)alloc((size_t)2 * S_TOK * CDIM * 2);
  int2*   ti_e   = (int2*)alloc((size_t)S_TOK * 8);
  int2*   ti_slot= (int2*)alloc((size_t)S_TOK * 8);
  float2* ti_w   = (float2*)alloc((size_t)S_TOK * 8);
  int*    cnt    = (int*)alloc(64);
  int*    offs   = (int*)alloc(64);
  int*    gidx   = (int*)alloc((size_t)2 * S_TOK * 4);

  // router + deterministic gather build (no atomics anywhere)
  router_kernel<<<S_TOK / 4, 256, 0, stream>>>(x, wg, gb, ti_e, ti_w);
  build_kernel<<<1, 1024, 0, stream>>>(ti_e, cnt, offs, gidx, ti_slot);

  // prep
  cast_bf16_kernel<<<2048, 256, 0, stream>>>(x, xb, S_TOK * CDIM / 4);
  wprep_in_kernel<<<dim3(H2 / 32, CDIM / 32, 2), 256, 0, stream>>>(wsi, w1s, w12i);
  transpose_cast_kernel<<<dim3(CDIM / 32, HDIM / 32, 1), 256, 0, stream>>>(wso, wso_t, HDIM, CDIM);
  transpose_cast_kernel<<<dim3(CDIM / 32, HDIM / 32, NEXP), 256, 0, stream>>>(w2, w2t, HDIM, CDIM);

  // stage 1: both hiddens in one GEMM, swiglu fused
  gemm1_kernel<<<dim3(S_TOK / BM, (2 * H2) / BN), NTHR, 0, stream>>>(xb, w12i, Hs, Hr);

  // stage 2: dense shared-out + ragged routed experts
  gemm2_kernel<<<dim3(32 + MAXRT, CDIM / BN), NTHR, 0, stream>>>(
      Hs, Hr, wso_t, w2t, cnt, offs, gidx, out, Eout);

  // scatter routed contributions into out
  scatter_kernel<<<2048, 256, 0, stream>>>(out, Eout, ti_e, ti_slot, ti_w, offs);
}

// Round 4
// 149.928 us; speedup vs baseline: 1.6682x; 1.0322x over previous
//
#include <hip/hip_runtime.h>
#include <stdint.h>

typedef __attribute__((ext_vector_type(4))) float f32x4;
typedef __attribute__((ext_vector_type(8))) short s16x8;

static constexpr int S_TOK = 4096;   // B*T
static constexpr int CDIM  = 1024;
static constexpr int HDIM  = 1024;
static constexpr int H2    = 2048;
static constexpr int NEXP  = 8;

#define BM 128
#define BN 128
#define BK 32
#define NTHR 512
#define MAXRT2 40   // max routed 256-row tiles: 8192/256 + 8 partials

__device__ __forceinline__ unsigned short f2bf(float f) {
  union { float f; uint32_t u; } c; c.f = f;
  uint32_t u = c.u;
  u += 0x7fffu + ((u >> 16) & 1u);   // RNE
  return (unsigned short)(u >> 16);
}

__device__ __forceinline__ float bf2f(unsigned short u) {
  return __uint_as_float(((uint32_t)u) << 16);
}

__device__ __forceinline__ void gload16(const void* g, void* l) {
  __builtin_amdgcn_global_load_lds(
      (const __attribute__((address_space(1))) void*)g,
      (__attribute__((address_space(3))) void*)l, 16, 0, 0);
}

// ---------- cast fp32 -> bf16 (x4) ----------
__global__ void cast_bf16_kernel(const float* __restrict__ src,
                                 unsigned short* __restrict__ dst, int n4) {
  int i = blockIdx.x * blockDim.x + threadIdx.x;
  const int st = gridDim.x * blockDim.x;
  for (; i < n4; i += st) {
    float4 v = reinterpret_cast<const float4*>(src)[i];
    ushort4 o;
    o.x = f2bf(v.x); o.y = f2bf(v.y); o.z = f2bf(v.z); o.w = f2bf(v.w);
    reinterpret_cast<ushort4*>(dst)[i] = o;
  }
}

// ---------- w_in prep: fp32 [C, 2H] -> bf16 [4096, C] part-interleaved ----------
__global__ void wprep_in_kernel(const float* __restrict__ wsi, const float* __restrict__ w1s,
                                unsigned short* __restrict__ dst) {
  __shared__ float t[32][33];
  const float* src = blockIdx.z ? w1s : wsi;
  const int halfoff = blockIdx.z ? 2048 : 0;
  const int r0 = blockIdx.y * 32;   // C dim
  const int c0 = blockIdx.x * 32;   // 2H dim
  const int tid = threadIdx.x;
#pragma unroll
  for (int i = 0; i < 4; ++i) {
    int idx = tid + i * 256;
    int r = idx >> 5, c = idx & 31;
    t[r][c] = src[(size_t)(r0 + r) * H2 + c0 + c];
  }
  __syncthreads();
#pragma unroll
  for (int i = 0; i < 4; ++i) {
    int idx = tid + i * 256;
    int r = idx >> 5, c = idx & 31;
    const int ccol = c0 + r;
    const int part = ccol >> 10, h = ccol & 1023;
    const int drow = halfoff + (h & 15) + ((h >> 4) << 5) + (part << 4);
    dst[(size_t)drow * CDIM + r0 + c] = f2bf(t[c][r]);
  }
}

// ---------- plain transpose + cast: fp32 [R, Cc] -> bf16 [Cc, R] ----------
__global__ void transpose_cast_kernel(const float* __restrict__ src,
                                      unsigned short* __restrict__ dst,
                                      int R, int Cc) {
  __shared__ float t[32][33];
  const size_t zoff = (size_t)blockIdx.z * R * Cc;
  src += zoff; dst += zoff;
  const int r0 = blockIdx.y * 32;
  const int c0 = blockIdx.x * 32;
  const int tid = threadIdx.x;
#pragma unroll
  for (int i = 0; i < 4; ++i) {
    int idx = tid + i * 256;
    int r = idx >> 5, c = idx & 31;
    t[r][c] = src[(size_t)(r0 + r) * Cc + c0 + c];
  }
  __syncthreads();
#pragma unroll
  for (int i = 0; i < 4; ++i) {
    int idx = tid + i * 256;
    int r = idx >> 5, c = idx & 31;
    dst[(size_t)(c0 + r) * R + r0 + c] = f2bf(t[c][r]);
  }
}

// ---------- router: fp32 logits, softmax, top-2. NO atomics. ----------
__global__ void router_kernel(const float* __restrict__ x, const float* __restrict__ wg,
                              const float* __restrict__ gb,
                              int2* __restrict__ ti_e, float2* __restrict__ ti_w) {
  const int l = threadIdx.x & 63;
  const int wid = threadIdx.x >> 6;
  const int s = blockIdx.x * 4 + wid;
  const float* xr = x + (size_t)s * CDIM;
  float acc[NEXP];
#pragma unroll
  for (int e = 0; e < NEXP; ++e) acc[e] = 0.f;
  for (int c = l; c < CDIM; c += 64) {
    float xv = xr[c];
    const float* wr_ = wg + (size_t)c * NEXP;
#pragma unroll
    for (int e = 0; e < NEXP; ++e) acc[e] += xv * wr_[e];
  }
#pragma unroll
  for (int e = 0; e < NEXP; ++e) {
#pragma unroll
    for (int off = 32; off > 0; off >>= 1) acc[e] += __shfl_xor(acc[e], off);
    acc[e] += gb[e];
  }
  float m = acc[0];
#pragma unroll
  for (int e = 1; e < NEXP; ++e) m = fmaxf(m, acc[e]);
  float ex[NEXP], sum = 0.f;
#pragma unroll
  for (int e = 0; e < NEXP; ++e) { ex[e] = __expf(acc[e] - m); sum += ex[e]; }
  int i0 = 0;
#pragma unroll
  for (int e = 1; e < NEXP; ++e) if (acc[e] > acc[i0]) i0 = e;  // lowest idx on tie
  int i1 = (i0 == 0) ? 1 : 0;
#pragma unroll
  for (int e = 0; e < NEXP; ++e) {
    if (e == i0) continue;
    if (acc[e] > acc[i1]) i1 = e;
  }
  if (l == 0) {
    const float inv = 1.f / sum;
    ti_e[s] = make_int2(i0, i1);
    ti_w[s] = make_float2(ex[i0] * inv, ex[i1] * inv);
  }
}

// ---------- build: deterministic counts/offsets/ranks/gather via ballot scan ----------
__global__ __launch_bounds__(1024) void build_kernel(
    const int2* __restrict__ ti_e,
    int* __restrict__ cnt, int* __restrict__ offs,
    int* __restrict__ gidx, int2* __restrict__ ti_slot) {
  __shared__ int gcnt[64][NEXP];
  __shared__ int gbase[64][NEXP];
  __shared__ int eoff[NEXP];
  const int tid = threadIdx.x;
  const int wid = tid >> 6, lane = tid & 63;

  for (int p = 0; p < 4; ++p) {
    const int g = p * 16 + wid;
    const int2 e = ti_e[g * 64 + lane];
#pragma unroll
    for (int ex = 0; ex < NEXP; ++ex) {
      uint64_t b0 = __ballot(e.x == ex);
      uint64_t b1 = __ballot(e.y == ex);
      if (lane == 0) gcnt[g][ex] = __popcll(b0) + __popcll(b1);
    }
  }
  __syncthreads();
  if (tid < NEXP) {
    const int ex = tid;
    int a = 0;
    for (int g = 0; g < 64; ++g) { gbase[g][ex] = a; a += gcnt[g][ex]; }
    eoff[ex] = a;
  }
  __syncthreads();
  if (tid == 0) {
    int a = 0;
#pragma unroll
    for (int ex = 0; ex < NEXP; ++ex) {
      const int c = eoff[ex];
      offs[ex] = a; cnt[ex] = c; eoff[ex] = a; a += c;
    }
    offs[NEXP] = a;
  }
  __syncthreads();
  for (int p = 0; p < 4; ++p) {
    const int g = p * 16 + wid;
    const int s = g * 64 + lane;
    const int2 e = ti_e[s];
    const uint64_t below = (lane == 0) ? 0ull : (~0ull >> (64 - lane));
    const uint64_t beloweq = below | (1ull << lane);
    int slot0 = 0, slot1 = 0;
#pragma unroll
    for (int ex = 0; ex < NEXP; ++ex) {
      uint64_t b0 = __ballot(e.x == ex);
      uint64_t b1 = __ballot(e.y == ex);
      const int base = gbase[g][ex];
      if (e.x == ex) slot0 = base + __popcll(b0 & below) + __popcll(b1 & below);
      if (e.y == ex) slot1 = base + __popcll(b0 & beloweq) + __popcll(b1 & below);
    }
    ti_slot[s] = make_int2(slot0, slot1);
    gidx[eoff[e.x] + slot0] = s;
    gidx[eoff[e.y] + slot1] = s;
  }
}

// ---------- 128x128 MFMA core (m97 structure) — used by gemm1 ----------
__device__ __forceinline__ void ktile_mfma(const unsigned short* As, const unsigned short* Bs,
                                           int lr, int lk, int wr, int wc, f32x4 acc[2][4]) {
  s16x8 a[2], b[4];
#pragma unroll
  for (int fm = 0; fm < 2; ++fm)
    a[fm] = *reinterpret_cast<const s16x8*>(As + (wr * 32 + fm * 16 + lr) * BK + lk);
#pragma unroll
  for (int fn = 0; fn < 4; ++fn)
    b[fn] = *reinterpret_cast<const s16x8*>(Bs + (wc * 64 + fn * 16 + lr) * BK + lk);
#pragma unroll
  for (int fm = 0; fm < 2; ++fm)
#pragma unroll
    for (int fn = 0; fn < 4; ++fn)
      acc[fm][fn] = __builtin_amdgcn_mfma_f32_16x16x32_bf16(a[fm], b[fn], acc[fm][fn], 0, 0, 0);
}

// ---------- GEMM1: hid = swiglu(x @ [wsi|w1s]) fused -> Hs, Hr bf16 (128x128, XCD swz) ----------
__global__ __launch_bounds__(NTHR) void gemm1_kernel(
    const unsigned short* __restrict__ xb, const unsigned short* __restrict__ w12i,
    unsigned short* __restrict__ Hs, unsigned short* __restrict__ Hr) {
  __shared__ unsigned short As[BM * BK];
  __shared__ unsigned short Bs[BN * BK];
  const int tid = threadIdx.x;
  const int l = tid & 63, wid = tid >> 6;
  const int wr = wid >> 1, wc = wid & 1;
  const int lr = l & 15, lk = (l >> 4) << 3;
  // XCD swizzle: grid 32x32=1024, chunk 128/XCD, n fastest within chunk
  const int hw = blockIdx.y * gridDim.x + blockIdx.x;
  const int logical = (hw & 7) * 128 + (hw >> 3);
  const int m0 = (logical >> 5) * BM;        // 32 n-tiles
  const int n0 = (logical & 31) * BN;
  f32x4 acc[2][4] = {};
  const unsigned short* ga = xb + (size_t)(m0 + (tid >> 2)) * CDIM + ((tid & 3) << 3);
  const unsigned short* gb = w12i + (size_t)(n0 + (tid >> 2)) * CDIM + ((tid & 3) << 3);
  for (int k0 = 0; k0 < 1024; k0 += BK) {
    gload16(ga + k0, As + tid * 8);
    gload16(gb + k0, Bs + tid * 8);
    __syncthreads();
    ktile_mfma(As, Bs, lr, lk, wr, wc, acc);
    __syncthreads();
  }
  unsigned short* Hbuf = (n0 < 2048) ? Hs : Hr;
  const int rb = m0 + wr * 32 + ((l >> 4) << 2);
  const int hbase = ((n0 & 2047) >> 1) + wc * 32;
#pragma unroll
  for (int fm = 0; fm < 2; ++fm)
#pragma unroll
    for (int j = 0; j < 2; ++j)
#pragma unroll
      for (int r = 0; r < 4; ++r) {
        float a = acc[fm][2 * j][r];
        float b = acc[fm][2 * j + 1][r];
        float hv = (a / (1.f + __expf(-a))) * b;
        Hbuf[(size_t)(rb + fm * 16 + r) * HDIM + hbase + j * 16 + lr] = f2bf(hv);
      }
}

// ---------- GEMM2: 256x256 tiles. dense shared-out + ragged routed ----------
// 8 waves as 2m x 4n; wave tile 128x64; acc[8][4].
__global__ __launch_bounds__(NTHR) void gemm2_kernel(
    const unsigned short* __restrict__ Hs, const unsigned short* __restrict__ Hr,
    const unsigned short* __restrict__ wso_t, const unsigned short* __restrict__ w2t,
    const int* __restrict__ cnt, const int* __restrict__ offs, const int* __restrict__ gidx,
    float* __restrict__ out, unsigned short* __restrict__ Eout) {
  __shared__ unsigned short As[256 * BK];
  __shared__ unsigned short Bs[256 * BK];
  const int tid = threadIdx.x;
  const int l = tid & 63, wid = tid >> 6;
  const int wm = wid >> 2, wn = wid & 3;
  const int lr = l & 15, lk = (l >> 4) << 3;
  // XCD swizzle: grid 56x4=224, chunk 28/XCD, n fastest
  const int hw = blockIdx.y * gridDim.x + blockIdx.x;
  const int logical = (hw & 7) * 28 + (hw >> 3);
  const int gx = logical >> 2;          // 0..55: 16 dense m-tiles then ragged tiles
  const int n0 = (logical & 3) * 256;
  f32x4 acc[8][4] = {};

  const int stage_row = tid >> 2;            // 0..127
  const int stage_col = (tid & 3) << 3;

  const unsigned short* ga0;
  const unsigned short* ga1;
  const unsigned short* gb0;
  const unsigned short* gb1;
  int e = 0, cnte = 0, mt = 0, base = 0;
  const bool dense = (gx < 16);
  if (dense) {
    const int m0 = gx * 256;
    ga0 = Hs + (size_t)(m0 + stage_row) * HDIM + stage_col;
    ga1 = ga0 + (size_t)128 * HDIM;
    gb0 = wso_t + (size_t)(n0 + stage_row) * HDIM + stage_col;
    gb1 = gb0 + (size_t)128 * HDIM;
  } else {
    int t = gx - 16;
    bool found = false;
#pragma unroll
    for (int ee = 0; ee < NEXP; ++ee) {
      int c = cnt[ee];
      int nt = (c + 255) >> 8;
      if (!found) {
        if (t < nt) { e = ee; cnte = c; found = true; }
        else t -= nt;
      }
    }
    if (!found) return;
    mt = t;
    base = offs[e];
    const int g0 = mt * 256 + stage_row;
    const int g1 = g0 + 128;
    const int tok0 = gidx[base + min(g0, cnte - 1)];
    const int tok1 = gidx[base + min(g1, cnte - 1)];
    ga0 = Hr + (size_t)tok0 * HDIM + stage_col;
    ga1 = Hr + (size_t)tok1 * HDIM + stage_col;
    gb0 = w2t + (size_t)e * CDIM * HDIM + (size_t)(n0 + stage_row) * HDIM + stage_col;
    gb1 = gb0 + (size_t)128 * HDIM;
  }

  for (int k0 = 0; k0 < 1024; k0 += BK) {
    gload16(ga0 + k0, As + tid * 8);
    gload16(ga1 + k0, As + tid * 8 + 128 * BK);
    gload16(gb0 + k0, Bs + tid * 8);
    gload16(gb1 + k0, Bs + tid * 8 + 128 * BK);
    __syncthreads();
    s16x8 a[8], b[4];
#pragma unroll
    for (int fm = 0; fm < 8; ++fm)
      a[fm] = *reinterpret_cast<const s16x8*>(As + (wm * 128 + fm * 16 + lr) * BK + lk);
#pragma unroll
    for (int fn = 0; fn < 4; ++fn)
      b[fn] = *reinterpret_cast<const s16x8*>(Bs + (wn * 64 + fn * 16 + lr) * BK + lk);
#pragma unroll
    for (int fm = 0; fm < 8; ++fm)
#pragma unroll
      for (int fn = 0; fn < 4; ++fn)
        acc[fm][fn] = __builtin_amdgcn_mfma_f32_16x16x32_bf16(a[fm], b[fn], acc[fm][fn], 0, 0, 0);
    __syncthreads();
  }

  const int rloc0 = wm * 128 + ((l >> 4) << 2);
  const int cb = n0 + wn * 64 + lr;
  if (dense) {
    const int rb = gx * 256 + rloc0;
#pragma unroll
    for (int fm = 0; fm < 8; ++fm)
#pragma unroll
      for (int fn = 0; fn < 4; ++fn)
#pragma unroll
        for (int r = 0; r < 4; ++r)
          out[(size_t)(rb + fm * 16 + r) * CDIM + cb + fn * 16] = acc[fm][fn][r];
  } else {
#pragma unroll
    for (int fm = 0; fm < 8; ++fm)
#pragma unroll
      for (int fn = 0; fn < 4; ++fn)
#pragma unroll
        for (int r = 0; r < 4; ++r) {
          const int rloc = mt * 256 + rloc0 + fm * 16 + r;
          if (rloc < cnte)
            Eout[(size_t)(base + rloc) * CDIM + cb + fn * 16] = f2bf(acc[fm][fn][r]);
        }
  }
}

// ---------- scatter: out[s] += w0*Eout[p0] + w1*Eout[p1] ----------
__global__ void scatter_kernel(float* __restrict__ out, const unsigned short* __restrict__ Eout,
                               const int2* __restrict__ ti_e, const int2* __restrict__ ti_slot,
                               const float2* __restrict__ ti_w, const int* __restrict__ offs) {
  const int total = S_TOK * (CDIM / 8);
  int i = blockIdx.x * blockDim.x + threadIdx.x;
  const int st = gridDim.x * blockDim.x;
  for (; i < total; i += st) {
    const int s = i >> 7;
    const int j = (i & 127) << 3;
    const int2 e = ti_e[s];
    const int2 sl = ti_slot[s];
    const float2 wv = ti_w[s];
    const int p0 = offs[e.x] + sl.x;
    const int p1 = offs[e.y] + sl.y;
    const ushort4* e0 = reinterpret_cast<const ushort4*>(Eout + (size_t)p0 * CDIM + j);
    const ushort4* e1 = reinterpret_cast<const ushort4*>(Eout + (size_t)p1 * CDIM + j);
    float* op = out + (size_t)s * CDIM + j;
#pragma unroll
    for (int q = 0; q < 2; ++q) {
      ushort4 a = e0[q], b = e1[q];
      float4 o = reinterpret_cast<float4*>(op)[q];
      o.x += wv.x * bf2f(a.x) + wv.y * bf2f(b.x);
      o.y += wv.x * bf2f(a.y) + wv.y * bf2f(b.y);
      o.z += wv.x * bf2f(a.z) + wv.y * bf2f(b.z);
      o.w += wv.x * bf2f(a.w) + wv.y * bf2f(b.w);
      reinterpret_cast<float4*>(op)[q] = o;
    }
  }
}

extern "C" void kernel_launch(void* const* d_in, const int* in_sizes, int n_in,
                              void* d_out, int out_size, void* d_ws, size_t ws_size,
                              hipStream_t stream) {
  (void)in_sizes; (void)n_in; (void)out_size; (void)ws_size;
  const float* x   = (const float*)d_in[0];
  const float* wsi = (const float*)d_in[1];   // [C, 2H]
  const float* wso = (const float*)d_in[2];   // [H, C]
  const float* w1s = (const float*)d_in[3];   // [C, 2H]
  const float* w2  = (const float*)d_in[4];   // [E, H, C]
  const float* wg  = (const float*)d_in[5];   // [C, E]
  const float* gb  = (const float*)d_in[6];   // [E]
  float* out = (float*)d_out;

  char* w = (char*)d_ws;
  auto alloc = [&](size_t bytes) {
    char* p = w; w += (bytes + 255) & ~(size_t)255; return p;
  };
  unsigned short* xb    = (unsigned short*)alloc((size_t)S_TOK * CDIM * 2);
  unsigned short* w12i  = (unsigned short*)alloc((size_t)2 * H2 * CDIM * 2);
  unsigned short* wso_t = (unsigned short*)alloc((size_t)CDIM * HDIM * 2);
  unsigned short* w2t   = (unsigned short*)alloc((size_t)NEXP * CDIM * HDIM * 2);
  unsigned short* Hs    = (unsigned short*)alloc((size_t)S_TOK * HDIM * 2);
  unsigned short* Hr    = (unsigned short*)alloc((size_t)S_TOK * HDIM * 2);
  unsigned short* Eout  = (unsigned short*)alloc((size_t)2 * S_TOK * CDIM * 2);
  int2*   ti_e   = (int2*)alloc((size_t)S_TOK * 8);
  int2*   ti_slot= (int2*)alloc((size_t)S_TOK * 8);
  float2* ti_w   = (float2*)alloc((size_t)S_TOK * 8);
  int*    cnt    = (int*)alloc(64);
  int*    offs   = (int*)alloc(64);
  int*    gidx   = (int*)alloc((size_t)2 * S_TOK * 4);

  // router + deterministic gather build (no atomics anywhere)
  router_kernel<<<S_TOK / 4, 256, 0, stream>>>(x, wg, gb, ti_e, ti_w);
  build_kernel<<<1, 1024, 0, stream>>>(ti_e, cnt, offs, gidx, ti_slot);

  // prep
  cast_bf16_kernel<<<2048, 256, 0, stream>>>(x, xb, S_TOK * CDIM / 4);
  wprep_in_kernel<<<dim3(H2 / 32, CDIM / 32, 2), 256, 0, stream>>>(wsi, w1s, w12i);
  transpose_cast_kernel<<<dim3(CDIM / 32, HDIM / 32, 1), 256, 0, stream>>>(wso, wso_t, HDIM, CDIM);
  transpose_cast_kernel<<<dim3(CDIM / 32, HDIM / 32, NEXP), 256, 0, stream>>>(w2, w2t, HDIM, CDIM);

  // stage 1: both hiddens in one GEMM, swiglu fused (128x128, XCD swizzle)
  gemm1_kernel<<<dim3(S_TOK / BM, (2 * H2) / BN), NTHR, 0, stream>>>(xb, w12i, Hs, Hr);

  // stage 2: 256x256 tiles, dense shared-out + ragged routed (XCD swizzle)
  gemm2_kernel<<<dim3(16 + MAXRT2, CDIM / 256), NTHR, 0, stream>>>(
      Hs, Hr, wso_t, w2t, cnt, offs, gidx, out, Eout);

  // scatter routed contributions into out
  scatter_kernel<<<2048, 256, 0, stream>>>(out, Eout, ti_e, ti_slot, ti_w, offs);
}

// Round 5
// 144.954 us; speedup vs baseline: 1.7255x; 1.0343x over previous
//
#include <hip/hip_runtime.h>
#include <stdint.h>

typedef __attribute__((ext_vector_type(4))) float f32x4;
typedef __attribute__((ext_vector_type(8))) short s16x8;

static constexpr int S_TOK = 4096;   // B*T
static constexpr int CDIM  = 1024;
static constexpr int HDIM  = 1024;
static constexpr int H2    = 2048;
static constexpr int NEXP  = 8;

#define BM 128
#define BN 128
#define BK 32
#define NTHR 512
#define MAXRT2 40   // max routed 256-row tiles: 8192/256 + 8 partials

__device__ __forceinline__ unsigned short f2bf(float f) {
  union { float f; uint32_t u; } c; c.f = f;
  uint32_t u = c.u;
  u += 0x7fffu + ((u >> 16) & 1u);   // RNE
  return (unsigned short)(u >> 16);
}

__device__ __forceinline__ float bf2f(unsigned short u) {
  return __uint_as_float(((uint32_t)u) << 16);
}

__device__ __forceinline__ void gload16(const void* g, void* l) {
  __builtin_amdgcn_global_load_lds(
      (const __attribute__((address_space(1))) void*)g,
      (__attribute__((address_space(3))) void*)l, 16, 0, 0);
}

__device__ __forceinline__ void barrier_mem() {
  asm volatile("" ::: "memory");
  __builtin_amdgcn_s_barrier();
  asm volatile("" ::: "memory");
}

// ---------- cast fp32 -> bf16 (x4) ----------
__global__ void cast_bf16_kernel(const float* __restrict__ src,
                                 unsigned short* __restrict__ dst, int n4) {
  int i = blockIdx.x * blockDim.x + threadIdx.x;
  const int st = gridDim.x * blockDim.x;
  for (; i < n4; i += st) {
    float4 v = reinterpret_cast<const float4*>(src)[i];
    ushort4 o;
    o.x = f2bf(v.x); o.y = f2bf(v.y); o.z = f2bf(v.z); o.w = f2bf(v.w);
    reinterpret_cast<ushort4*>(dst)[i] = o;
  }
}

// ---------- w_in prep: fp32 [C, 2H] -> bf16 [4096, C] part-interleaved ----------
__global__ void wprep_in_kernel(const float* __restrict__ wsi, const float* __restrict__ w1s,
                                unsigned short* __restrict__ dst) {
  __shared__ float t[32][33];
  const float* src = blockIdx.z ? w1s : wsi;
  const int halfoff = blockIdx.z ? 2048 : 0;
  const int r0 = blockIdx.y * 32;   // C dim
  const int c0 = blockIdx.x * 32;   // 2H dim
  const int tid = threadIdx.x;
#pragma unroll
  for (int i = 0; i < 4; ++i) {
    int idx = tid + i * 256;
    int r = idx >> 5, c = idx & 31;
    t[r][c] = src[(size_t)(r0 + r) * H2 + c0 + c];
  }
  __syncthreads();
#pragma unroll
  for (int i = 0; i < 4; ++i) {
    int idx = tid + i * 256;
    int r = idx >> 5, c = idx & 31;
    const int ccol = c0 + r;
    const int part = ccol >> 10, h = ccol & 1023;
    const int drow = halfoff + (h & 15) + ((h >> 4) << 5) + (part << 4);
    dst[(size_t)drow * CDIM + r0 + c] = f2bf(t[c][r]);
  }
}

// ---------- plain transpose + cast: fp32 [R, Cc] -> bf16 [Cc, R] ----------
__global__ void transpose_cast_kernel(const float* __restrict__ src,
                                      unsigned short* __restrict__ dst,
                                      int R, int Cc) {
  __shared__ float t[32][33];
  const size_t zoff = (size_t)blockIdx.z * R * Cc;
  src += zoff; dst += zoff;
  const int r0 = blockIdx.y * 32;
  const int c0 = blockIdx.x * 32;
  const int tid = threadIdx.x;
#pragma unroll
  for (int i = 0; i < 4; ++i) {
    int idx = tid + i * 256;
    int r = idx >> 5, c = idx & 31;
    t[r][c] = src[(size_t)(r0 + r) * Cc + c0 + c];
  }
  __syncthreads();
#pragma unroll
  for (int i = 0; i < 4; ++i) {
    int idx = tid + i * 256;
    int r = idx >> 5, c = idx & 31;
    dst[(size_t)(c0 + r) * R + r0 + c] = f2bf(t[c][r]);
  }
}

// ---------- router: fp32 logits, softmax, top-2. NO atomics. ----------
__global__ void router_kernel(const float* __restrict__ x, const float* __restrict__ wg,
                              const float* __restrict__ gb,
                              int2* __restrict__ ti_e, float2* __restrict__ ti_w) {
  const int l = threadIdx.x & 63;
  const int wid = threadIdx.x >> 6;
  const int s = blockIdx.x * 4 + wid;
  const float* xr = x + (size_t)s * CDIM;
  float acc[NEXP];
#pragma unroll
  for (int e = 0; e < NEXP; ++e) acc[e] = 0.f;
  for (int c = l; c < CDIM; c += 64) {
    float xv = xr[c];
    const float* wr_ = wg + (size_t)c * NEXP;
#pragma unroll
    for (int e = 0; e < NEXP; ++e) acc[e] += xv * wr_[e];
  }
#pragma unroll
  for (int e = 0; e < NEXP; ++e) {
#pragma unroll
    for (int off = 32; off > 0; off >>= 1) acc[e] += __shfl_xor(acc[e], off);
    acc[e] += gb[e];
  }
  float m = acc[0];
#pragma unroll
  for (int e = 1; e < NEXP; ++e) m = fmaxf(m, acc[e]);
  float ex[NEXP], sum = 0.f;
#pragma unroll
  for (int e = 0; e < NEXP; ++e) { ex[e] = __expf(acc[e] - m); sum += ex[e]; }
  int i0 = 0;
#pragma unroll
  for (int e = 1; e < NEXP; ++e) if (acc[e] > acc[i0]) i0 = e;  // lowest idx on tie
  int i1 = (i0 == 0) ? 1 : 0;
#pragma unroll
  for (int e = 0; e < NEXP; ++e) {
    if (e == i0) continue;
    if (acc[e] > acc[i1]) i1 = e;
  }
  if (l == 0) {
    const float inv = 1.f / sum;
    ti_e[s] = make_int2(i0, i1);
    ti_w[s] = make_float2(ex[i0] * inv, ex[i1] * inv);
  }
}

// ---------- build: deterministic counts/offsets/ranks/gather via ballot scan ----------
__global__ __launch_bounds__(1024) void build_kernel(
    const int2* __restrict__ ti_e,
    int* __restrict__ cnt, int* __restrict__ offs,
    int* __restrict__ gidx, int2* __restrict__ ti_slot) {
  __shared__ int gcnt[64][NEXP];
  __shared__ int gbase[64][NEXP];
  __shared__ int eoff[NEXP];
  const int tid = threadIdx.x;
  const int wid = tid >> 6, lane = tid & 63;

  for (int p = 0; p < 4; ++p) {
    const int g = p * 16 + wid;
    const int2 e = ti_e[g * 64 + lane];
#pragma unroll
    for (int ex = 0; ex < NEXP; ++ex) {
      uint64_t b0 = __ballot(e.x == ex);
      uint64_t b1 = __ballot(e.y == ex);
      if (lane == 0) gcnt[g][ex] = __popcll(b0) + __popcll(b1);
    }
  }
  __syncthreads();
  if (tid < NEXP) {
    const int ex = tid;
    int a = 0;
    for (int g = 0; g < 64; ++g) { gbase[g][ex] = a; a += gcnt[g][ex]; }
    eoff[ex] = a;
  }
  __syncthreads();
  if (tid == 0) {
    int a = 0;
#pragma unroll
    for (int ex = 0; ex < NEXP; ++ex) {
      const int c = eoff[ex];
      offs[ex] = a; cnt[ex] = c; eoff[ex] = a; a += c;
    }
    offs[NEXP] = a;
  }
  __syncthreads();
  for (int p = 0; p < 4; ++p) {
    const int g = p * 16 + wid;
    const int s = g * 64 + lane;
    const int2 e = ti_e[s];
    const uint64_t below = (lane == 0) ? 0ull : (~0ull >> (64 - lane));
    const uint64_t beloweq = below | (1ull << lane);
    int slot0 = 0, slot1 = 0;
#pragma unroll
    for (int ex = 0; ex < NEXP; ++ex) {
      uint64_t b0 = __ballot(e.x == ex);
      uint64_t b1 = __ballot(e.y == ex);
      const int base = gbase[g][ex];
      if (e.x == ex) slot0 = base + __popcll(b0 & below) + __popcll(b1 & below);
      if (e.y == ex) slot1 = base + __popcll(b0 & beloweq) + __popcll(b1 & below);
    }
    ti_slot[s] = make_int2(slot0, slot1);
    gidx[eoff[e.x] + slot0] = s;
    gidx[eoff[e.y] + slot1] = s;
  }
}

// ---------- 128x128 MFMA core (m97 structure) — used by gemm1 ----------
__device__ __forceinline__ void ktile_mfma(const unsigned short* As, const unsigned short* Bs,
                                           int lr, int lk, int wr, int wc, f32x4 acc[2][4]) {
  s16x8 a[2], b[4];
#pragma unroll
  for (int fm = 0; fm < 2; ++fm)
    a[fm] = *reinterpret_cast<const s16x8*>(As + (wr * 32 + fm * 16 + lr) * BK + lk);
#pragma unroll
  for (int fn = 0; fn < 4; ++fn)
    b[fn] = *reinterpret_cast<const s16x8*>(Bs + (wc * 64 + fn * 16 + lr) * BK + lk);
#pragma unroll
  for (int fm = 0; fm < 2; ++fm)
#pragma unroll
    for (int fn = 0; fn < 4; ++fn)
      acc[fm][fn] = __builtin_amdgcn_mfma_f32_16x16x32_bf16(a[fm], b[fn], acc[fm][fn], 0, 0, 0);
}

// ---------- GEMM1: hid = swiglu(x @ [wsi|w1s]) fused -> Hs, Hr bf16 (128x128, XCD swz) ----------
__global__ __launch_bounds__(NTHR) void gemm1_kernel(
    const unsigned short* __restrict__ xb, const unsigned short* __restrict__ w12i,
    unsigned short* __restrict__ Hs, unsigned short* __restrict__ Hr) {
  __shared__ unsigned short As[BM * BK];
  __shared__ unsigned short Bs[BN * BK];
  const int tid = threadIdx.x;
  const int l = tid & 63, wid = tid >> 6;
  const int wr = wid >> 1, wc = wid & 1;
  const int lr = l & 15, lk = (l >> 4) << 3;
  // XCD swizzle: grid 32x32=1024, chunk 128/XCD, n fastest within chunk
  const int hw = blockIdx.y * gridDim.x + blockIdx.x;
  const int logical = (hw & 7) * 128 + (hw >> 3);
  const int m0 = (logical >> 5) * BM;        // 32 n-tiles
  const int n0 = (logical & 31) * BN;
  f32x4 acc[2][4] = {};
  const unsigned short* ga = xb + (size_t)(m0 + (tid >> 2)) * CDIM + ((tid & 3) << 3);
  const unsigned short* gb = w12i + (size_t)(n0 + (tid >> 2)) * CDIM + ((tid & 3) << 3);
  for (int k0 = 0; k0 < 1024; k0 += BK) {
    gload16(ga + k0, As + tid * 8);
    gload16(gb + k0, Bs + tid * 8);
    __syncthreads();
    ktile_mfma(As, Bs, lr, lk, wr, wc, acc);
    __syncthreads();
  }
  unsigned short* Hbuf = (n0 < 2048) ? Hs : Hr;
  const int rb = m0 + wr * 32 + ((l >> 4) << 2);
  const int hbase = ((n0 & 2047) >> 1) + wc * 32;
#pragma unroll
  for (int fm = 0; fm < 2; ++fm)
#pragma unroll
    for (int j = 0; j < 2; ++j)
#pragma unroll
      for (int r = 0; r < 4; ++r) {
        float a = acc[fm][2 * j][r];
        float b = acc[fm][2 * j + 1][r];
        float hv = (a / (1.f + __expf(-a))) * b;
        Hbuf[(size_t)(rb + fm * 16 + r) * HDIM + hbase + j * 16 + lr] = f2bf(hv);
      }
}

// ---------- GEMM2: 256x256 tiles, 2-phase double-buffered pipeline (counted vmcnt) ----------
// 8 waves as 2m x 4n; wave tile 128x64; acc[8][4].
__global__ __launch_bounds__(NTHR) void gemm2_kernel(
    const unsigned short* __restrict__ Hs, const unsigned short* __restrict__ Hr,
    const unsigned short* __restrict__ wso_t, const unsigned short* __restrict__ w2t,
    const int* __restrict__ cnt, const int* __restrict__ offs, const int* __restrict__ gidx,
    float* __restrict__ out, unsigned short* __restrict__ Eout) {
  __shared__ unsigned short As[2][256 * BK];
  __shared__ unsigned short Bs[2][256 * BK];
  const int tid = threadIdx.x;
  const int l = tid & 63, wid = tid >> 6;
  const int wm = wid >> 2, wn = wid & 3;
  const int lr = l & 15, lk = (l >> 4) << 3;
  // XCD swizzle: grid 56x4=224, chunk 28/XCD, n fastest
  const int hw = blockIdx.y * gridDim.x + blockIdx.x;
  const int logical = (hw & 7) * 28 + (hw >> 3);
  const int gx = logical >> 2;          // 0..55: 16 dense m-tiles then ragged tiles
  const int n0 = (logical & 3) * 256;
  f32x4 acc[8][4] = {};

  const int stage_row = tid >> 2;            // 0..127
  const int stage_col = (tid & 3) << 3;

  const unsigned short* ga0;
  const unsigned short* ga1;
  const unsigned short* gb0;
  const unsigned short* gb1;
  int e = 0, cnte = 0, mt = 0, base = 0;
  const bool dense = (gx < 16);
  if (dense) {
    const int m0 = gx * 256;
    ga0 = Hs + (size_t)(m0 + stage_row) * HDIM + stage_col;
    ga1 = ga0 + (size_t)128 * HDIM;
    gb0 = wso_t + (size_t)(n0 + stage_row) * HDIM + stage_col;
    gb1 = gb0 + (size_t)128 * HDIM;
  } else {
    int t = gx - 16;
    bool found = false;
#pragma unroll
    for (int ee = 0; ee < NEXP; ++ee) {
      int c = cnt[ee];
      int nt = (c + 255) >> 8;
      if (!found) {
        if (t < nt) { e = ee; cnte = c; found = true; }
        else t -= nt;
      }
    }
    if (!found) return;
    mt = t;
    base = offs[e];
    const int g0 = mt * 256 + stage_row;
    const int g1 = g0 + 128;
    const int tok0 = gidx[base + min(g0, cnte - 1)];
    const int tok1 = gidx[base + min(g1, cnte - 1)];
    ga0 = Hr + (size_t)tok0 * HDIM + stage_col;
    ga1 = Hr + (size_t)tok1 * HDIM + stage_col;
    gb0 = w2t + (size_t)e * CDIM * HDIM + (size_t)(n0 + stage_row) * HDIM + stage_col;
    gb1 = gb0 + (size_t)128 * HDIM;
  }

  // stage one K-tile (4 gload_lds per thread) into buffer `buf`
#define STAGE2(buf, k0) do { \
    gload16(ga0 + (k0), As[buf] + tid * 8); \
    gload16(ga1 + (k0), As[buf] + 4096 + tid * 8); \
    gload16(gb0 + (k0), Bs[buf] + tid * 8); \
    gload16(gb1 + (k0), Bs[buf] + 4096 + tid * 8); \
  } while (0)

  // prologue: stage tile 0, drain, sync
  STAGE2(0, 0);
  asm volatile("s_waitcnt vmcnt(0)" ::: "memory");
  barrier_mem();

  const int NT = 1024 / BK;   // 32 K-tiles
  for (int t = 0; t < NT; ++t) {
    const int cur = t & 1;
    if (t + 1 < NT) STAGE2(cur ^ 1, (t + 1) * BK);
    if (t > 0) {
      // wait for buf[cur]'s 4 loads (issued last iter); leave the 4 just issued in flight
      if (t + 1 < NT) asm volatile("s_waitcnt vmcnt(4)" ::: "memory");
      else            asm volatile("s_waitcnt vmcnt(0)" ::: "memory");
      barrier_mem();   // all waves' portions of buf[cur] arrived
    }
    {
      const unsigned short* Ac = As[cur];
      const unsigned short* Bc = Bs[cur];
      s16x8 a[8], b[4];
#pragma unroll
      for (int fm = 0; fm < 8; ++fm)
        a[fm] = *reinterpret_cast<const s16x8*>(Ac + (wm * 128 + fm * 16 + lr) * BK + lk);
#pragma unroll
      for (int fn = 0; fn < 4; ++fn)
        b[fn] = *reinterpret_cast<const s16x8*>(Bc + (wn * 64 + fn * 16 + lr) * BK + lk);
#pragma unroll
      for (int fm = 0; fm < 8; ++fm)
#pragma unroll
        for (int fn = 0; fn < 4; ++fn)
          acc[fm][fn] = __builtin_amdgcn_mfma_f32_16x16x32_bf16(a[fm], b[fn], acc[fm][fn], 0, 0, 0);
    }
    barrier_mem();   // all waves done reading buf[cur] before it is overwritten next iter
  }
#undef STAGE2

  const int rloc0 = wm * 128 + ((l >> 4) << 2);
  const int cb = n0 + wn * 64 + lr;
  if (dense) {
    const int rb = gx * 256 + rloc0;
#pragma unroll
    for (int fm = 0; fm < 8; ++fm)
#pragma unroll
      for (int fn = 0; fn < 4; ++fn)
#pragma unroll
        for (int r = 0; r < 4; ++r)
          out[(size_t)(rb + fm * 16 + r) * CDIM + cb + fn * 16] = acc[fm][fn][r];
  } else {
#pragma unroll
    for (int fm = 0; fm < 8; ++fm)
#pragma unroll
      for (int fn = 0; fn < 4; ++fn)
#pragma unroll
        for (int r = 0; r < 4; ++r) {
          const int rloc = mt * 256 + rloc0 + fm * 16 + r;
          if (rloc < cnte)
            Eout[(size_t)(base + rloc) * CDIM + cb + fn * 16] = f2bf(acc[fm][fn][r]);
        }
  }
}

// ---------- scatter: out[s] += w0*Eout[p0] + w1*Eout[p1] ----------
__global__ void scatter_kernel(float* __restrict__ out, const unsigned short* __restrict__ Eout,
                               const int2* __restrict__ ti_e, const int2* __restrict__ ti_slot,
                               const float2* __restrict__ ti_w, const int* __restrict__ offs) {
  const int total = S_TOK * (CDIM / 8);
  int i = blockIdx.x * blockDim.x + threadIdx.x;
  const int st = gridDim.x * blockDim.x;
  for (; i < total; i += st) {
    const int s = i >> 7;
    const int j = (i & 127) << 3;
    const int2 e = ti_e[s];
    const int2 sl = ti_slot[s];
    const float2 wv = ti_w[s];
    const int p0 = offs[e.x] + sl.x;
    const int p1 = offs[e.y] + sl.y;
    const ushort4* e0 = reinterpret_cast<const ushort4*>(Eout + (size_t)p0 * CDIM + j);
    const ushort4* e1 = reinterpret_cast<const ushort4*>(Eout + (size_t)p1 * CDIM + j);
    float* op = out + (size_t)s * CDIM + j;
#pragma unroll
    for (int q = 0; q < 2; ++q) {
      ushort4 a = e0[q], b = e1[q];
      float4 o = reinterpret_cast<float4*>(op)[q];
      o.x += wv.x * bf2f(a.x) + wv.y * bf2f(b.x);
      o.y += wv.x * bf2f(a.y) + wv.y * bf2f(b.y);
      o.z += wv.x * bf2f(a.z) + wv.y * bf2f(b.z);
      o.w += wv.x * bf2f(a.w) + wv.y * bf2f(b.w);
      reinterpret_cast<float4*>(op)[q] = o;
    }
  }
}

extern "C" void kernel_launch(void* const* d_in, const int* in_sizes, int n_in,
                              void* d_out, int out_size, void* d_ws, size_t ws_size,
                              hipStream_t stream) {
  (void)in_sizes; (void)n_in; (void)out_size; (void)ws_size;
  const float* x   = (const float*)d_in[0];
  const float* wsi = (const float*)d_in[1];   // [C, 2H]
  const float* wso = (const float*)d_in[2];   // [H, C]
  const float* w1s = (const float*)d_in[3];   // [C, 2H]
  const float* w2  = (const float*)d_in[4];   // [E, H, C]
  const float* wg  = (const float*)d_in[5];   // [C, E]
  const float* gb  = (const float*)d_in[6];   // [E]
  float* out = (float*)d_out;

  char* w = (char*)d_ws;
  auto alloc = [&](size_t bytes) {
    char* p = w; w += (bytes + 255) & ~(size_t)255; return p;
  };
  unsigned short* xb    = (unsigned short*)alloc((size_t)S_TOK * CDIM * 2);
  unsigned short* w12i  = (unsigned short*)alloc((size_t)2 * H2 * CDIM * 2);
  unsigned short* wso_t = (unsigned short*)alloc((size_t)CDIM * HDIM * 2);
  unsigned short* w2t   = (unsigned short*)alloc((size_t)NEXP * CDIM * HDIM * 2);
  unsigned short* Hs    = (unsigned short*)alloc((size_t)S_TOK * HDIM * 2);
  unsigned short* Hr    = (unsigned short*)alloc((size_t)S_TOK * HDIM * 2);
  unsigned short* Eout  = (unsigned short*)alloc((size_t)2 * S_TOK * CDIM * 2);
  int2*   ti_e   = (int2*)alloc((size_t)S_TOK * 8);
  int2*   ti_slot= (int2*)alloc((size_t)S_TOK * 8);
  float2* ti_w   = (float2*)alloc((size_t)S_TOK * 8);
  int*    cnt    = (int*)alloc(64);
  int*    offs   = (int*)alloc(64);
  int*    gidx   = (int*)alloc((size_t)2 * S_TOK * 4);

  // router + deterministic gather build (no atomics anywhere)
  router_kernel<<<S_TOK / 4, 256, 0, stream>>>(x, wg, gb, ti_e, ti_w);
  build_kernel<<<1, 1024, 0, stream>>>(ti_e, cnt, offs, gidx, ti_slot);

  // prep
  cast_bf16_kernel<<<2048, 256, 0, stream>>>(x, xb, S_TOK * CDIM / 4);
  wprep_in_kernel<<<dim3(H2 / 32, CDIM / 32, 2), 256, 0, stream>>>(wsi, w1s, w12i);
  transpose_cast_kernel<<<dim3(CDIM / 32, HDIM / 32, 1), 256, 0, stream>>>(wso, wso_t, HDIM, CDIM);
  transpose_cast_kernel<<<dim3(CDIM / 32, HDIM / 32, NEXP), 256, 0, stream>>>(w2, w2t, HDIM, CDIM);

  // stage 1: both hiddens in one GEMM, swiglu fused (128x128, XCD swizzle)
  gemm1_kernel<<<dim3(S_TOK / BM, (2 * H2) / BN), NTHR, 0, stream>>>(xb, w12i, Hs, Hr);

  // stage 2: 256x256 tiles, 2-phase dbuf pipeline, dense + ragged (XCD swizzle)
  gemm2_kernel<<<dim3(16 + MAXRT2, CDIM / 256), NTHR, 0, stream>>>(
      Hs, Hr, wso_t, w2t, cnt, offs, gidx, out, Eout);

  // scatter routed contributions into out
  scatter_kernel<<<2048, 256, 0, stream>>>(out, Eout, ti_e, ti_slot, ti_w, offs);
}